// Round 12
// baseline (883.200 us; speedup 1.0000x reference)
//
#include <hip/hip_runtime.h>
#include <hip/hip_cooperative_groups.h>
#include <hip/hip_fp16.h>
#include <math.h>

namespace cg = cooperative_groups;

#define N_NODES 50000
#define N_EDGES 800000
#define BIGV 1000000000.0f
#define NBLK_SCAN 196   // ceil(50000/256)
#define N_TILES 3125    // 50000 / 16 nodes per tile

typedef _Float16 half8 __attribute__((ext_vector_type(8)));
typedef float floatx4 __attribute__((ext_vector_type(4)));

__device__ __forceinline__ float clampinf(float x) { return isinf(x) ? BIGV : x; }

// shared-memory union across phases
union SH {
    struct { _Float16 hA[16][136]; float spart[4][16]; float tpart[4][16]; } g;
    struct { int rs[256]; int s[256]; } sc;
    struct { float ls[256]; float lq[256]; } bn;
};

// ---------------------------------------------------------------------------
// k_pre: W^T fp16 cast + zero cursor/bns (one small dispatch).
// ---------------------------------------------------------------------------
__global__ __launch_bounds__(256) void k_pre(const float* __restrict__ W,
                                             __half* __restrict__ wt,
                                             int* __restrict__ cursor,
                                             float* __restrict__ bns)
{
    int idx = blockIdx.x * 256 + threadIdx.x;   // 0..16383
    int n = idx >> 7, k = idx & 127;
    wt[idx] = __float2half(W[k * 128 + n]);
    for (int i = idx; i < N_NODES; i += 16384) cursor[i] = 0;
    if (idx < 256) bns[idx] = 0.f;
}

// ---------------------------------------------------------------------------
// k_mega: the whole pipeline after k_pre, phases separated by grid.sync().
//   G: GEMM (MFMA f16) + fused scores + fused histogram/rank  [R11-proven]
//   A: scan block sums   B: root+local scan -> colptr
//   C: scatter (atomic-free)   D: per-node softmax aggregate
//   E: BN stats          F: BN apply + ELU
// ---------------------------------------------------------------------------
__global__ __launch_bounds__(256) void k_mega(
    const float* __restrict__ h, const __half* __restrict__ wt,
    const float* __restrict__ bias, const float* __restrict__ attn_w,
    const int* __restrict__ src, const int* __restrict__ dst,
    const float* __restrict__ sigma, const float* __restrict__ attn_b,
    __half* __restrict__ zh, float* __restrict__ sv, float* __restrict__ tv,
    int* __restrict__ cursor, int* __restrict__ rank,
    int* __restrict__ bsum, int* __restrict__ colptr,
    float4* __restrict__ recs, float* __restrict__ out,
    float* __restrict__ bns, const float* __restrict__ gamma,
    const float* __restrict__ beta)
{
    __shared__ SH sh;
    cg::grid_group grid = cg::this_grid();

    const int tid = threadIdx.x;
    const int lane = tid & 63;
    const int wv = tid >> 6;
    const int l16 = lane & 15;
    const int oct = lane >> 4;

    // ===================== phase G: GEMM =====================
    {
        const int n0 = wv << 5;   // wave's 32-col strip
        half8 bfrag[4][2];
        #pragma unroll
        for (int kk = 0; kk < 4; ++kk)
            #pragma unroll
            for (int t = 0; t < 2; ++t)
                bfrag[kk][t] = *(const half8*)(wt + (size_t)(n0 + t * 16 + l16) * 128
                                                  + kk * 32 + oct * 8);
        const float bv0 = bias[n0 + l16],         bv1 = bias[n0 + 16 + l16];
        const float ws0 = attn_w[n0 + l16],       ws1 = attn_w[n0 + 16 + l16];
        const float wd0 = attn_w[128 + n0 + l16], wd1 = attn_w[128 + n0 + 16 + l16];

        for (int tile = blockIdx.x; tile < N_TILES; tile += gridDim.x) {
            const int node0 = tile << 4;
            const int e = tile * 256 + tid;
            const int d = dst[e];
            __syncthreads();   // hA/spart reuse across tile iterations
            {
                const float4* h4 = (const float4*)(h + (size_t)node0 * 128);
                for (int i = tid; i < 512; i += 256) {
                    int r = i >> 5, c4 = i & 31;
                    float4 v = h4[i];
                    union { __half2 h2[2]; uint2 u; } pk;
                    pk.h2[0] = __floats2half2_rn(v.x, v.y);
                    pk.h2[1] = __floats2half2_rn(v.z, v.w);
                    *(uint2*)&sh.g.hA[r][c4 << 2] = pk.u;
                }
            }
            rank[e] = atomicAdd(&cursor[d], 1);
            __syncthreads();

            floatx4 acc0 = {0.f, 0.f, 0.f, 0.f};
            floatx4 acc1 = {0.f, 0.f, 0.f, 0.f};
            #pragma unroll
            for (int kk = 0; kk < 4; ++kk) {
                half8 a = *(const half8*)&sh.g.hA[l16][(kk << 5) + (oct << 3)];
                acc0 = __builtin_amdgcn_mfma_f32_16x16x32_f16(a, bfrag[kk][0], acc0, 0, 0, 0);
                acc1 = __builtin_amdgcn_mfma_f32_16x16x32_f16(a, bfrag[kk][1], acc1, 0, 0, 0);
            }

            float s_acc[4], t_acc[4];
            #pragma unroll
            for (int r = 0; r < 4; ++r) {
                float z0 = clampinf(acc0[r] + bv0);
                float z1 = clampinf(acc1[r] + bv1);
                const int row = (oct << 2) + r;
                zh[(size_t)(node0 + row) * 128 + n0 + l16]      = __float2half(z0);
                zh[(size_t)(node0 + row) * 128 + n0 + 16 + l16] = __float2half(z1);
                s_acc[r] = z0 * ws0 + z1 * ws1;
                t_acc[r] = z0 * wd0 + z1 * wd1;
            }
            #pragma unroll
            for (int r = 0; r < 4; ++r) {
                #pragma unroll
                for (int o = 1; o < 16; o <<= 1) {
                    s_acc[r] += __shfl_xor(s_acc[r], o);
                    t_acc[r] += __shfl_xor(t_acc[r], o);
                }
            }
            if (l16 == 0) {
                #pragma unroll
                for (int r = 0; r < 4; ++r) {
                    sh.g.spart[wv][(oct << 2) + r] = s_acc[r];
                    sh.g.tpart[wv][(oct << 2) + r] = t_acc[r];
                }
            }
            __syncthreads();
            if (tid < 16) {
                sv[node0 + tid] = sh.g.spart[0][tid] + sh.g.spart[1][tid]
                                + sh.g.spart[2][tid] + sh.g.spart[3][tid];
                tv[node0 + tid] = sh.g.tpart[0][tid] + sh.g.tpart[1][tid]
                                + sh.g.tpart[2][tid] + sh.g.tpart[3][tid];
            }
        }
    }
    __threadfence();
    grid.sync();

    // ===================== phase A: scan block sums =====================
    if (blockIdx.x < NBLK_SCAN) {
        const int idx = blockIdx.x * 256 + tid;
        sh.sc.s[tid] = (idx < N_NODES) ? cursor[idx] : 0;
        __syncthreads();
        for (int off = 128; off; off >>= 1) {
            if (tid < off) sh.sc.s[tid] += sh.sc.s[tid + off];
            __syncthreads();
        }
        if (tid == 0) bsum[blockIdx.x] = sh.sc.s[0];
    }
    __threadfence();
    grid.sync();

    // ===================== phase B: root + local scan -> colptr =========
    if (blockIdx.x < NBLK_SCAN) {
        int rv = (tid < NBLK_SCAN) ? bsum[tid] : 0;
        sh.sc.rs[tid] = rv;
        __syncthreads();
        for (int off = 1; off < 256; off <<= 1) {
            int u = (tid >= off) ? sh.sc.rs[tid - off] : 0;
            __syncthreads();
            sh.sc.rs[tid] += u;
            __syncthreads();
        }
        const int broot = (blockIdx.x > 0) ? sh.sc.rs[blockIdx.x - 1] : 0;
        if (blockIdx.x == 0 && tid == 255) colptr[N_NODES] = sh.sc.rs[255];

        const int idx = blockIdx.x * 256 + tid;
        int v = (idx < N_NODES) ? cursor[idx] : 0;
        sh.sc.s[tid] = v;
        __syncthreads();
        for (int off = 1; off < 256; off <<= 1) {
            int u = (tid >= off) ? sh.sc.s[tid - off] : 0;
            __syncthreads();
            sh.sc.s[tid] += u;
            __syncthreads();
        }
        if (idx < N_NODES) colptr[idx] = broot + sh.sc.s[tid] - v;
    }
    __threadfence();
    grid.sync();

    // ===================== phase C: scatter (atomic-free) ===============
    for (int e = blockIdx.x * 256 + tid; e < N_EDGES; e += gridDim.x * 256) {
        int s = src[e];
        int d = dst[e];
        float a = sv[s] + tv[d] + attn_b[0];
        a = clampinf(a);
        float ev = a > 0.f ? a : 0.01f * a;      // leaky relu
        int pos = colptr[d] + rank[e];
        float4 rec;
        rec.x = __int_as_float(s);
        rec.y = sigma[e];
        rec.z = ev;
        rec.w = 0.f;
        recs[pos] = rec;
    }
    __threadfence();
    grid.sync();

    // ===================== phase D: softmax aggregate ===================
    for (int g4 = blockIdx.x; g4 < N_NODES / 4; g4 += gridDim.x) {
        const int node = g4 * 4 + wv;            // always < N_NODES
        const int base = colptr[node];
        const int deg = colptr[node + 1] - base;
        const int grp = oct;
        float acc[8] = {0.f, 0.f, 0.f, 0.f, 0.f, 0.f, 0.f, 0.f};

        if (deg > 0) {
            if (deg <= 64) {
                int sidx = 0; float sig = 0.f, e = -INFINITY;
                if (lane < deg) {
                    float4 r = recs[base + lane];
                    sidx = __float_as_int(r.x); sig = r.y; e = r.z;
                }
                float m = e;
                for (int o = 32; o; o >>= 1) m = fmaxf(m, __shfl_xor(m, o));
                float p = (lane < deg) ? __expf(e - m) : 0.f;
                float dn = p, bs = sig;
                for (int o = 32; o; o >>= 1) {
                    dn += __shfl_xor(dn, o);
                    bs += __shfl_xor(bs, o);
                }
                const float coef = p * sig * (1.0f / dn) / (bs + 1e-6f);
                for (int c = 0; c < deg; c += 4) {
                    const int j = c + grp;
                    const int js = (j < deg) ? j : 0;
                    float cf = __shfl(coef, js);     // wave-uniform shuffles
                    int sj = __shfl(sidx, js);
                    if (j < deg) {
                        uint4 raw = *(const uint4*)(zh + ((size_t)sj << 7) + (l16 << 3));
                        const __half2* hp = (const __half2*)&raw;
                        #pragma unroll
                        for (int k = 0; k < 4; ++k) {
                            float2 f = __half22float2(hp[k]);
                            acc[2*k]   = fmaf(cf, f.x, acc[2*k]);
                            acc[2*k+1] = fmaf(cf, f.y, acc[2*k+1]);
                        }
                    }
                }
            } else {
                float m = -INFINITY;
                for (int i = lane; i < deg; i += 64) m = fmaxf(m, recs[base + i].z);
                for (int o = 32; o; o >>= 1) m = fmaxf(m, __shfl_xor(m, o));
                float dn = 0.f, bs = 0.f;
                for (int i = lane; i < deg; i += 64) {
                    float4 r = recs[base + i];
                    dn += __expf(r.z - m); bs += r.y;
                }
                for (int o = 32; o; o >>= 1) {
                    dn += __shfl_xor(dn, o);
                    bs += __shfl_xor(bs, o);
                }
                const float scale = (1.0f / dn) / (bs + 1e-6f);
                for (int c = 0; c < deg; c += 64) {
                    int i = c + lane;
                    int sidx = 0; float coef = 0.f;
                    if (i < deg) {
                        float4 r = recs[base + i];
                        sidx = __float_as_int(r.x);
                        coef = __expf(r.z - m) * r.y * scale;
                    }
                    const int cnt = min(64, deg - c);
                    for (int j = 0; j < cnt; j += 4) {
                        const int jj = j + grp;
                        const int js = (jj < cnt) ? jj : 0;
                        float cf = __shfl(coef, js);
                        int sj = __shfl(sidx, js);
                        if (jj < cnt) {
                            uint4 raw = *(const uint4*)(zh + ((size_t)sj << 7) + (l16 << 3));
                            const __half2* hp = (const __half2*)&raw;
                            #pragma unroll
                            for (int k = 0; k < 4; ++k) {
                                float2 f = __half22float2(hp[k]);
                                acc[2*k]   = fmaf(cf, f.x, acc[2*k]);
                                acc[2*k+1] = fmaf(cf, f.y, acc[2*k+1]);
                            }
                        }
                    }
                }
            }
        }
        #pragma unroll
        for (int k = 0; k < 8; ++k) {
            acc[k] += __shfl_xor(acc[k], 16);
            acc[k] += __shfl_xor(acc[k], 32);
        }
        if (grp == 0) {
            float4 o0, o1;
            o0.x = clampinf(acc[0]); o0.y = clampinf(acc[1]);
            o0.z = clampinf(acc[2]); o0.w = clampinf(acc[3]);
            o1.x = clampinf(acc[4]); o1.y = clampinf(acc[5]);
            o1.z = clampinf(acc[6]); o1.w = clampinf(acc[7]);
            float4* op = (float4*)(out + (size_t)node * 128 + (l16 << 3));
            op[0] = o0; op[1] = o1;
        }
    }
    __threadfence();
    grid.sync();

    // ===================== phase E: BN stats ============================
    {
        const int f = tid & 127;
        const int half_ = tid >> 7;
        float s = 0.f, q = 0.f;
        for (int node = blockIdx.x * 2 + half_; node < N_NODES; node += gridDim.x * 2) {
            float v = out[(size_t)node * 128 + f];
            s += v;
            q += v * v;
        }
        sh.bn.ls[tid] = s; sh.bn.lq[tid] = q;
        __syncthreads();
        if (half_ == 0) {
            s += sh.bn.ls[tid + 128];
            q += sh.bn.lq[tid + 128];
            atomicAdd(&bns[f], s);
            atomicAdd(&bns[128 + f], q);
        }
    }
    __threadfence();
    grid.sync();

    // ===================== phase F: BN apply + ELU ======================
    {
        const float invn = 1.0f / (float)N_NODES;
        const float4* s4 = (const float4*)bns;
        const float4* q4 = (const float4*)(bns + 128);
        const float4* g4p = (const float4*)gamma;
        const float4* b4p = (const float4*)beta;
        float4* io4 = (float4*)out;
        const int total4 = (N_NODES * 128) / 4;   // 1.6M
        for (int i = blockIdx.x * 256 + tid; i < total4; i += gridDim.x * 256) {
            const int f4 = i & 31;
            float4 sm = s4[f4], sq = q4[f4], gm = g4p[f4], bt = b4p[f4];
            float4 x = io4[i], y;
            {
                float mu = sm.x * invn, var = fmaxf(sq.x * invn - mu * mu, 0.f);
                float r = rsqrtf(var + 1e-5f);
                float t = (x.x - mu) * r * gm.x + bt.x;
                y.x = t > 0.f ? t : expm1f(t);
            }
            {
                float mu = sm.y * invn, var = fmaxf(sq.y * invn - mu * mu, 0.f);
                float r = rsqrtf(var + 1e-5f);
                float t = (x.y - mu) * r * gm.y + bt.y;
                y.y = t > 0.f ? t : expm1f(t);
            }
            {
                float mu = sm.z * invn, var = fmaxf(sq.z * invn - mu * mu, 0.f);
                float r = rsqrtf(var + 1e-5f);
                float t = (x.z - mu) * r * gm.z + bt.z;
                y.z = t > 0.f ? t : expm1f(t);
            }
            {
                float mu = sm.w * invn, var = fmaxf(sq.w * invn - mu * mu, 0.f);
                float r = rsqrtf(var + 1e-5f);
                float t = (x.w - mu) * r * gm.w + bt.w;
                y.w = t > 0.f ? t : expm1f(t);
            }
            io4[i] = y;
        }
    }
}

// ---------------------------------------------------------------------------
extern "C" void kernel_launch(void* const* d_in, const int* in_sizes, int n_in,
                              void* d_out, int out_size, void* d_ws, size_t ws_size,
                              hipStream_t stream)
{
    const float* h      = (const float*)d_in[0];
    const int*   src    = (const int*)  d_in[1];
    const int*   dst    = (const int*)  d_in[2];
    const float* sigma  = (const float*)d_in[3];
    const float* fc_w   = (const float*)d_in[4];
    const float* fc_b   = (const float*)d_in[5];
    const float* attn_w = (const float*)d_in[6];
    const float* attn_b = (const float*)d_in[7];
    const float* gamma  = (const float*)d_in[8];
    const float* beta   = (const float*)d_in[9];
    float* out = (float*)d_out;

    // workspace layout (~30 MB)
    float4* recs   = (float4*)d_ws;                         // 800000 x 16B
    __half* zh     = (__half*)(recs + N_EDGES);             // 50000*128 fp16
    float*  sv     = (float*)(zh + (size_t)N_NODES * 128);  // 50000
    float*  tv     = sv + N_NODES;                          // 50000
    float*  bns    = tv + N_NODES;                          // 256
    int*    colptr = (int*)(bns + 256);                     // 50001 (pad 50004)
    int*    cursor = colptr + 50004;                        // 50000
    int*    bsum   = cursor + N_NODES;                      // 196 (pad 256)
    int*    broot  = bsum + 256;                            // (pad, unused)
    __half* wt     = (__half*)(broot + 256);                // 128*128 fp16 (W^T)
    int*    rank   = (int*)(wt + 128 * 128);                // 800000

    // co-residency-safe grid size for the cooperative kernel
    int bpc = 0;
    hipOccupancyMaxActiveBlocksPerMultiprocessor(&bpc, k_mega, 256, 0);
    if (bpc < 1) bpc = 1;
    long long grid_ll = (long long)bpc * 256;   // 256 CUs on MI355X
    if (grid_ll > N_TILES) grid_ll = N_TILES;
    int grid = (int)grid_ll;
    if (grid < 256) grid = 256;                 // scan phases need >=196 blocks

    k_pre<<<64, 256, 0, stream>>>(fc_w, wt, cursor, bns);

    void* args[] = { (void*)&h, (void*)&wt, (void*)&fc_b, (void*)&attn_w,
                     (void*)&src, (void*)&dst, (void*)&sigma, (void*)&attn_b,
                     (void*)&zh, (void*)&sv, (void*)&tv, (void*)&cursor,
                     (void*)&rank, (void*)&bsum, (void*)&colptr, (void*)&recs,
                     (void*)&out, (void*)&bns, (void*)&gamma, (void*)&beta };
    hipLaunchCooperativeKernel((void*)k_mega, dim3(grid), dim3(256), args, 0, stream);
}